// Round 18
// baseline (523.988 us; speedup 1.0000x reference)
//
#include <hip/hip_runtime.h>

#define EPS 1e-5f

typedef __attribute__((ext_vector_type(8))) short bf16x8;
typedef __attribute__((ext_vector_type(4))) float f32x4;

// round-to-nearest-even f32 -> bf16
static __device__ __forceinline__ ushort rn_bf16(float v) {
    unsigned u = __float_as_uint(v);
    unsigned r = u + 0x7FFFu + ((u >> 16) & 1u);
    return (ushort)(r >> 16);
}
static __device__ __forceinline__ float bf16f(ushort h) {
    return __uint_as_float(((unsigned)h) << 16);
}

// Split f32x4 -> 4 bf16 hi + 4 bf16 lo, both round-to-nearest (error ~2^-18|v|).
static __device__ __forceinline__ void split4(float4 f, ushort4& hi, ushort4& lo) {
    float v[4] = {f.x, f.y, f.z, f.w};
    ushort h[4], l[4];
#pragma unroll
    for (int i = 0; i < 4; ++i) {
        h[i] = rn_bf16(v[i]);
        l[i] = rn_bf16(v[i] - bf16f(h[i]));
    }
    hi = make_ushort4(h[0], h[1], h[2], h[3]);
    lo = make_ushort4(l[0], l[1], l[2], l[3]);
}

static __device__ __forceinline__ float4 bnrelu4(float4 v, float4 a, float4 d) {
    float4 r;
    r.x = fmaxf(a.x * v.x + d.x, 0.f);
    r.y = fmaxf(a.y * v.y + d.y, 0.f);
    r.z = fmaxf(a.z * v.z + d.z, 0.f);
    r.w = fmaxf(a.w * v.w + d.w, 0.f);
    return r;
}

// ================= CSR build =================
__global__ __launch_bounds__(256) void hist_kernel(
    const int* __restrict__ ei, int* __restrict__ deg, int E)
{
    int e = blockIdx.x * 256 + threadIdx.x;
    if (e >= E) return;
    atomicAdd(&deg[ei[E + e]], 1);
}

__global__ __launch_bounds__(256) void blocksum_kernel(
    const int* __restrict__ deg, int* __restrict__ bsum, int N)
{
    int i = blockIdx.x * 256 + threadIdx.x;
    int v = (i < N) ? deg[i] : 0;
#pragma unroll
    for (int o = 1; o < 64; o <<= 1) v += __shfl_xor(v, o);
    __shared__ int s[4];
    if ((threadIdx.x & 63) == 0) s[threadIdx.x >> 6] = v;
    __syncthreads();
    if (threadIdx.x == 0) bsum[blockIdx.x] = s[0] + s[1] + s[2] + s[3];
}

__global__ __launch_bounds__(512) void scanb_kernel(int* bsum, int NB)
{
    __shared__ int sh[512];
    int t = threadIdx.x;
    int v = (t < NB) ? bsum[t] : 0;
    sh[t] = v;
    __syncthreads();
    for (int o = 1; o < 512; o <<= 1) {
        int add = (t >= o) ? sh[t - o] : 0;
        __syncthreads();
        sh[t] += add;
        __syncthreads();
    }
    if (t < NB) bsum[t] = (t == 0) ? 0 : sh[t - 1];
}

__global__ __launch_bounds__(256) void scanfinal_kernel(
    const int* __restrict__ deg, const int* __restrict__ bsum,
    int* __restrict__ rowptr, int* __restrict__ cursor, int N)
{
    int b = blockIdx.x, t = threadIdx.x;
    int i = b * 256 + t;
    int v = (i < N) ? deg[i] : 0;
    __shared__ int sh[256];
    sh[t] = v;
    __syncthreads();
    for (int o = 1; o < 256; o <<= 1) {
        int add = (t >= o) ? sh[t - o] : 0;
        __syncthreads();
        sh[t] += add;
        __syncthreads();
    }
    int excl = sh[t] - v;
    if (i < N) {
        int rp = bsum[b] + excl;
        rowptr[i] = rp;
        cursor[i] = rp;
        if (i == N - 1) rowptr[N] = rp + v;
    }
}

__global__ __launch_bounds__(256) void fill_kernel(
    const int* __restrict__ ei, int* __restrict__ cursor, int* __restrict__ col, int E)
{
    int e = blockIdx.x * 256 + threadIdx.x;
    if (e >= E) return;
    int d = ei[E + e];
    int pos = atomicAdd(&cursor[d], 1);
    col[pos] = ei[e];
}

// Canonicalize: sort each row's col entries ascending -> gather sum order is a
// function of the multiset only (atomic fill order is scheduling-dependent).
__global__ __launch_bounds__(256) void sortrow_kernel(
    const int* __restrict__ rowptr, int* __restrict__ col, int N)
{
    int n = blockIdx.x * 256 + threadIdx.x;
    if (n >= N) return;
    int beg = rowptr[n], end = rowptr[n + 1];
    for (int i = beg + 1; i < end; ++i) {
        int v = col[i];
        int j = i - 1;
        while (j >= beg && col[j] > v) { col[j + 1] = col[j]; --j; }
        col[j + 1] = v;
    }
}

// ================= weight prepack: f32 [128][128] -> packed per-matrix [hi|lo] planes =================
__global__ __launch_bounds__(256) void prepack_kernel(
    const float* __restrict__ W0, const float* __restrict__ W1,
    const float* __restrict__ W2, const float* __restrict__ W3,
    const float* __restrict__ W4, const float* __restrict__ W5,
    ushort* __restrict__ wPk)
{
    int m = blockIdx.y;
    const float* W = (m == 0) ? W0 : (m == 1) ? W1 : (m == 2) ? W2
                   : (m == 3) ? W3 : (m == 4) ? W4 : W5;
    int base = m * 32768;
#pragma unroll
    for (int t = 0; t < 8; ++t) {
        int idx = blockIdx.x * 2048 + t * 256 + threadIdx.x;
        int j = idx & 7, l = (idx >> 3) & 63, cf = (idx >> 9) & 7, kb = idx >> 12;
        int k = kb * 32 + (l >> 4) * 8 + j;
        int n = cf * 16 + (l & 15);
        float v = W[k * 128 + n];
        ushort h = rn_bf16(v);
        wPk[base + idx] = h;
        wPk[base + 16384 + idx] = rn_bf16(v - bf16f(h));
    }
}

// ================= fused gather + dual MFMA linear + per-block stats (persistent) =================
// Y = agg(X)@Wl + X@Wr + bias.  Stats: per-block partials -> stPart (no atomics).
// r14's PASSING launch geometry: __launch_bounds__(512,2), grid 512.
template<int BN>
__global__ __launch_bounds__(512, 2) void glin_kernel(
    const float* __restrict__ X, const int* __restrict__ rowptr,
    const int* __restrict__ colIdx, const ushort* __restrict__ wPair,
    const float* __restrict__ bias, const float* __restrict__ bnst,
    float* __restrict__ Y, float* __restrict__ stPart, int nrows)
{
    // planes: [m][hi/lo][16 rows][136 bf16]; m0 = agg (Wl), m1 = root (Wr)
    __shared__ ushort ldsA[2 * 2 * 2176];
    const int tid  = threadIdx.x;
    const int lane = tid & 63;
    const int w    = tid >> 6;
    const int q = lane >> 4, s = lane & 15;

    // W fragments -> registers (once)
    bf16x8 wf[2][4][2];
#pragma unroll
    for (int m = 0; m < 2; ++m)
#pragma unroll
        for (int kb = 0; kb < 4; ++kb) {
            size_t o = (size_t)m * 32768 + (size_t)kb * 4096 + w * 512 + lane * 8;
            wf[m][kb][0] = *(const bf16x8*)(wPair + o);
            wf[m][kb][1] = *(const bf16x8*)(wPair + o + 16384);
        }

    const int srow  = tid >> 5;
    const int sunit = tid & 31;
    float4 bna, bnd;
    if (BN) {
        bna = *(const float4*)(bnst + 256 + sunit * 4);
        bnd = *(const float4*)(bnst + 384 + sunit * 4);
    }

    const int colc = w * 16 + s;
    const float bv = bias[colc];
    float cs = 0.f, cq = 0.f;

    const int NT = (nrows + 15) >> 4;
    const int stride = (int)gridDim.x;
    const int t0 = blockIdx.x;
    const int woff = srow * 136 + sunit * 4;

    auto stage = [&](int t) {
        int row = t * 16 + srow; if (row > nrows - 1) row = nrows - 1;
        float4 root = *(const float4*)(X + (size_t)row * 128 + sunit * 4);
        int beg = rowptr[row], end = rowptr[row + 1];
        float ax = 0.f, ay = 0.f, az = 0.f, aw = 0.f;
        float bx = 0.f, by = 0.f, bz = 0.f, bw = 0.f;
        int e = beg;
        for (; e + 2 <= end; e += 2) {
            int s0 = colIdx[e], s1 = colIdx[e + 1];
            float4 v0 = *(const float4*)(X + (size_t)s0 * 128 + sunit * 4);
            float4 v1 = *(const float4*)(X + (size_t)s1 * 128 + sunit * 4);
            if (BN) { v0 = bnrelu4(v0, bna, bnd); v1 = bnrelu4(v1, bna, bnd); }
            ax += v0.x; ay += v0.y; az += v0.z; aw += v0.w;
            bx += v1.x; by += v1.y; bz += v1.z; bw += v1.w;
        }
        if (e < end) {
            int s0 = colIdx[e];
            float4 v0 = *(const float4*)(X + (size_t)s0 * 128 + sunit * 4);
            if (BN) v0 = bnrelu4(v0, bna, bnd);
            ax += v0.x; ay += v0.y; az += v0.z; aw += v0.w;
        }
        float4 agg = make_float4(ax + bx, ay + by, az + bz, aw + bw);
        if (BN) root = bnrelu4(root, bna, bnd);
        ushort4 h, l;
        split4(agg, h, l);
        *(ushort4*)(ldsA + woff)        = h;
        *(ushort4*)(ldsA + 2176 + woff) = l;
        split4(root, h, l);
        *(ushort4*)(ldsA + 4352 + woff) = h;
        *(ushort4*)(ldsA + 6528 + woff) = l;
    };

    if (t0 < NT) stage(t0);

    for (int t = t0; t < NT; t += stride) {
        __syncthreads();   // staged planes visible

        f32x4 acc = (f32x4){0.f, 0.f, 0.f, 0.f};
#pragma unroll
        for (int m = 0; m < 2; ++m) {
            const ushort* pm = ldsA + m * 4352 + s * 136;
#pragma unroll
            for (int kb = 0; kb < 4; ++kb) {
                bf16x8 ah = *(const bf16x8*)(pm + (kb * 4 + q) * 8);
                bf16x8 al = *(const bf16x8*)(pm + 2176 + (kb * 4 + q) * 8);
                acc = __builtin_amdgcn_mfma_f32_16x16x32_bf16(ah, wf[m][kb][0], acc, 0, 0, 0);
                acc = __builtin_amdgcn_mfma_f32_16x16x32_bf16(al, wf[m][kb][0], acc, 0, 0, 0);
                acc = __builtin_amdgcn_mfma_f32_16x16x32_bf16(ah, wf[m][kb][1], acc, 0, 0, 0);
            }
        }

        int r0 = t * 16 + q * 4;
#pragma unroll
        for (int i = 0; i < 4; ++i) {
            int r = r0 + i;
            if (r < nrows) {
                float y = acc[i] + bv;
                Y[(size_t)r * 128 + colc] = y;
                cs += y; cq += y * y;
            }
        }
        __syncthreads();   // plane reads done
        int tn = t + stride;
        if (tn < NT) stage(tn);
    }

    // per-block partials, fixed shfl tree, no atomics -> deterministic
    cs += __shfl_xor(cs, 16); cs += __shfl_xor(cs, 32);
    cq += __shfl_xor(cq, 16); cq += __shfl_xor(cq, 32);
    if (q == 0) {
        stPart[(size_t)blockIdx.x * 256 + colc]       = cs;
        stPart[(size_t)blockIdx.x * 256 + 128 + colc] = cq;
    }
}

// ================= BN finalize: fixed-order reduce of partials -> affine (a, d) =================
__global__ __launch_bounds__(256) void finalize_kernel(
    const float* __restrict__ stPart, int nblocks, float* st,
    const float* __restrict__ g, const float* __restrict__ be, float inv_n)
{
    __shared__ float tot[256];
    int t = threadIdx.x;
    float acc = 0.f;
    for (int b = 0; b < nblocks; ++b)          // fixed order -> deterministic
        acc += stPart[(size_t)b * 256 + t];
    tot[t] = acc;
    __syncthreads();
    if (t < 128) {
        float mu = tot[t] * inv_n;
        float var = tot[128 + t] * inv_n - mu * mu;
        float rs = rsqrtf(var + EPS);
        float a = g[t] * rs;
        st[256 + t] = a;
        st[384 + t] = be[t] - mu * a;
    }
}

// ================= fused MLP head: out = relu(relu(bnrelu(X)@W1+b1)@W2+b2)@W3+b3 =================
__global__ __launch_bounds__(512, 2) void mlp_kernel(
    const float* __restrict__ X, const ushort* __restrict__ w1Pk,
    const ushort* __restrict__ w2Pk, const float* __restrict__ b1,
    const float* __restrict__ b2, const float* __restrict__ W3,
    const float* __restrict__ b3, const float* __restrict__ bnst,
    float* __restrict__ out, int nrows)
{
    __shared__ ushort ldsP[2 * 2176];    // hi/lo planes for current GEMM input
    __shared__ float  ldsY[16 * 132];    // y tile (132-pad)
    const int tid  = threadIdx.x;
    const int lane = tid & 63;
    const int w    = tid >> 6;
    const int q = lane >> 4, s = lane & 15;

    bf16x8 wf1[4][2], wf2[4][2];
#pragma unroll
    for (int kb = 0; kb < 4; ++kb) {
        size_t o = (size_t)kb * 4096 + w * 512 + lane * 8;
        wf1[kb][0] = *(const bf16x8*)(w1Pk + o);
        wf1[kb][1] = *(const bf16x8*)(w1Pk + o + 16384);
        wf2[kb][0] = *(const bf16x8*)(w2Pk + o);
        wf2[kb][1] = *(const bf16x8*)(w2Pk + o + 16384);
    }

    const int srow  = tid >> 5;
    const int sunit = tid & 31;
    float4 bna = *(const float4*)(bnst + 256 + sunit * 4);
    float4 bnd = *(const float4*)(bnst + 384 + sunit * 4);

    float w30[4], w31[4];
#pragma unroll
    for (int j = 0; j < 4; ++j) {
        w30[j] = W3[(sunit * 4 + j) * 2];
        w31[j] = W3[(sunit * 4 + j) * 2 + 1];
    }
    const float b30 = b3[0], b31 = b3[1];

    const int colc = w * 16 + s;
    const float bv1 = b1[colc];
    const float bv2 = b2[colc];

    const int NT = (nrows + 15) >> 4;
    const int stride = (int)gridDim.x;
    const int t0 = blockIdx.x;
    const int woff = srow * 136 + sunit * 4;

    auto stageX = [&](int t) {
        int row = t * 16 + srow; if (row > nrows - 1) row = nrows - 1;
        float4 v = *(const float4*)(X + (size_t)row * 128 + sunit * 4);
        v = bnrelu4(v, bna, bnd);
        ushort4 h, l;
        split4(v, h, l);
        *(ushort4*)(ldsP + woff)        = h;
        *(ushort4*)(ldsP + 2176 + woff) = l;
    };

    auto gemm = [&](const bf16x8 (&wf)[4][2]) {
        f32x4 acc = (f32x4){0.f, 0.f, 0.f, 0.f};
        const ushort* pm = ldsP + s * 136;
#pragma unroll
        for (int kb = 0; kb < 4; ++kb) {
            bf16x8 ah = *(const bf16x8*)(pm + (kb * 4 + q) * 8);
            bf16x8 al = *(const bf16x8*)(pm + 2176 + (kb * 4 + q) * 8);
            acc = __builtin_amdgcn_mfma_f32_16x16x32_bf16(ah, wf[kb][0], acc, 0, 0, 0);
            acc = __builtin_amdgcn_mfma_f32_16x16x32_bf16(al, wf[kb][0], acc, 0, 0, 0);
            acc = __builtin_amdgcn_mfma_f32_16x16x32_bf16(ah, wf[kb][1], acc, 0, 0, 0);
        }
        return acc;
    };

    if (t0 < NT) stageX(t0);

    for (int t = t0; t < NT; t += stride) {
        __syncthreads();                         // (a) planes(X) ready; prev dot's ldsY reads done

        f32x4 acc = gemm(wf1);
#pragma unroll
        for (int i = 0; i < 4; ++i)
            ldsY[(q * 4 + i) * 132 + colc] = fmaxf(acc[i] + bv1, 0.f);
        __syncthreads();                         // (c) y1 ready; planes(X) reads done

        {   // re-split y1 -> planes
            float4 yv = *(const float4*)&ldsY[srow * 132 + sunit * 4];
            ushort4 h, l;
            split4(yv, h, l);
            *(ushort4*)(ldsP + woff)        = h;
            *(ushort4*)(ldsP + 2176 + woff) = l;
        }
        __syncthreads();                         // (d) planes(y1) ready; y1 reads done

        acc = gemm(wf2);
#pragma unroll
        for (int i = 0; i < 4; ++i)
            ldsY[(q * 4 + i) * 132 + colc] = fmaxf(acc[i] + bv2, 0.f);
        __syncthreads();                         // (e) y2 ready; planes(y1) reads done

        {   // per-row projection to DOUT=2 (fixed shfl order -> deterministic)
            float4 yv = *(const float4*)&ldsY[srow * 132 + sunit * 4];
            float p0 = yv.x * w30[0] + yv.y * w30[1] + yv.z * w30[2] + yv.w * w30[3];
            float p1 = yv.x * w31[0] + yv.y * w31[1] + yv.z * w31[2] + yv.w * w31[3];
#pragma unroll
            for (int o = 1; o < 32; o <<= 1) {
                p0 += __shfl_xor(p0, o);
                p1 += __shfl_xor(p1, o);
            }
            int row = t * 16 + srow;
            if (sunit == 0 && row < nrows)
                *(float2*)(out + (size_t)row * 2) = make_float2(p0 + b30, p1 + b31);
        }
        int tn = t + stride;
        if (tn < NT) stageX(tn);                 // writes ldsP (reads done at (e))
    }
}

extern "C" void kernel_launch(void* const* d_in, const int* in_sizes, int n_in,
                              void* d_out, int out_size, void* d_ws, size_t ws_size,
                              hipStream_t stream) {
    const float* x   = (const float*)d_in[0];
    const int*   ei  = (const int*)d_in[1];
    const float* Wl0 = (const float*)d_in[2];
    const float* bl0 = (const float*)d_in[3];
    const float* Wr0 = (const float*)d_in[4];
    const float* Wl1 = (const float*)d_in[5];
    const float* bl1 = (const float*)d_in[6];
    const float* Wr1 = (const float*)d_in[7];
    const float* g0  = (const float*)d_in[8];
    const float* be0 = (const float*)d_in[9];
    const float* g1  = (const float*)d_in[10];
    const float* be1 = (const float*)d_in[11];
    const float* W1  = (const float*)d_in[12];
    const float* b1  = (const float*)d_in[13];
    const float* W2  = (const float*)d_in[14];
    const float* b2  = (const float*)d_in[15];
    const float* W3  = (const float*)d_in[16];
    const float* b3  = (const float*)d_in[17];
    float* out = (float*)d_out;

    const int N = in_sizes[0] / 128;
    const int E = in_sizes[1] / 2;
    const int GLIN_GRID = 512;

    // workspace layout
    float* A   = (float*)d_ws;                   // [N,128]
    float* B   = A + (size_t)N * 128;            // [N,128]
    float* st0 = B + (size_t)N * 128;            // 512 floats
    float* st1 = st0 + 512;                      // 512 floats
    float* stPart = st1 + 512;                   // GLIN_GRID * 256
    ushort* wPk = (ushort*)(stPart + (size_t)GLIN_GRID * 256);   // 6 * 32768
    int* deg    = (int*)(wPk + 6 * 32768);       // N
    int* rowptr = deg + N;                       // N+1
    int* cursor = rowptr + N + 1;                // N
    int* col    = cursor + N;                    // E
    int* bsum   = col + E;                       // <=512

    const int edgeGrid = (E + 255) / 256;
    const int nodeGrid = (N + 255) / 256;
    const float inv_n = 1.0f / (float)N;

    // matrix slots: 0=Wl0 1=Wr0 2=Wl1 3=Wr1 4=W1 5=W2 (dual pairs adjacent)
    prepack_kernel<<<dim3(8, 6), 256, 0, stream>>>(Wl0, Wr0, Wl1, Wr1, W1, W2, wPk);

    // ----- CSR build (canonicalized: per-row sort -> deterministic sum order) -----
    hipMemsetAsync(deg, 0, (size_t)N * sizeof(int), stream);
    hist_kernel<<<edgeGrid, 256, 0, stream>>>(ei, deg, E);
    blocksum_kernel<<<nodeGrid, 256, 0, stream>>>(deg, bsum, N);
    scanb_kernel<<<1, 512, 0, stream>>>(bsum, nodeGrid);
    scanfinal_kernel<<<nodeGrid, 256, 0, stream>>>(deg, bsum, rowptr, cursor, N);
    fill_kernel<<<edgeGrid, 256, 0, stream>>>(ei, cursor, col, E);
    sortrow_kernel<<<nodeGrid, 256, 0, stream>>>(rowptr, col, N);

    // ----- layer 0: A = agg(x)@Wl0 + x@Wr0 + bl0 (fused gather+lin), partials -> finalize -----
    glin_kernel<0><<<GLIN_GRID, 512, 0, stream>>>(
        x, rowptr, col, wPk, bl0, nullptr, A, stPart, N);
    finalize_kernel<<<1, 256, 0, stream>>>(stPart, GLIN_GRID, st0, g0, be0, inv_n);

    // ----- layer 1: B = agg(bn0(A))@Wl1 + bn0(A)@Wr1 + bl1 -----
    glin_kernel<1><<<GLIN_GRID, 512, 0, stream>>>(
        A, rowptr, col, wPk + 2 * 32768, bl1, st0, B, stPart, N);
    finalize_kernel<<<1, 256, 0, stream>>>(stPart, GLIN_GRID, st1, g1, be1, inv_n);

    // ----- fused MLP head + projection -----
    mlp_kernel<<<GLIN_GRID, 512, 0, stream>>>(
        B, wPk + 4 * 32768, wPk + 5 * 32768, b1, b2, W3, b3, st1, out, N);
}

// Round 19
// 291.423 us; speedup vs baseline: 1.7980x; 1.7980x over previous
//
#include <hip/hip_runtime.h>

#define EPS 1e-5f

typedef __attribute__((ext_vector_type(8))) short bf16x8;
typedef __attribute__((ext_vector_type(4))) float f32x4;

// round-to-nearest-even f32 -> bf16
static __device__ __forceinline__ ushort rn_bf16(float v) {
    unsigned u = __float_as_uint(v);
    unsigned r = u + 0x7FFFu + ((u >> 16) & 1u);
    return (ushort)(r >> 16);
}
static __device__ __forceinline__ float bf16f(ushort h) {
    return __uint_as_float(((unsigned)h) << 16);
}

// Split f32x4 -> 4 bf16 hi + 4 bf16 lo, both round-to-nearest (error ~2^-18|v|).
static __device__ __forceinline__ void split4(float4 f, ushort4& hi, ushort4& lo) {
    float v[4] = {f.x, f.y, f.z, f.w};
    ushort h[4], l[4];
#pragma unroll
    for (int i = 0; i < 4; ++i) {
        h[i] = rn_bf16(v[i]);
        l[i] = rn_bf16(v[i] - bf16f(h[i]));
    }
    hi = make_ushort4(h[0], h[1], h[2], h[3]);
    lo = make_ushort4(l[0], l[1], l[2], l[3]);
}

static __device__ __forceinline__ float4 bnrelu4(float4 v, float4 a, float4 d) {
    float4 r;
    r.x = fmaxf(a.x * v.x + d.x, 0.f);
    r.y = fmaxf(a.y * v.y + d.y, 0.f);
    r.z = fmaxf(a.z * v.z + d.z, 0.f);
    r.w = fmaxf(a.w * v.w + d.w, 0.f);
    return r;
}

// ================= CSR build =================
__global__ __launch_bounds__(256) void hist_kernel(
    const int* __restrict__ ei, int* __restrict__ deg, int E)
{
    int e = blockIdx.x * 256 + threadIdx.x;
    if (e >= E) return;
    atomicAdd(&deg[ei[E + e]], 1);
}

__global__ __launch_bounds__(256) void blocksum_kernel(
    const int* __restrict__ deg, int* __restrict__ bsum, int N)
{
    int i = blockIdx.x * 256 + threadIdx.x;
    int v = (i < N) ? deg[i] : 0;
#pragma unroll
    for (int o = 1; o < 64; o <<= 1) v += __shfl_xor(v, o);
    __shared__ int s[4];
    if ((threadIdx.x & 63) == 0) s[threadIdx.x >> 6] = v;
    __syncthreads();
    if (threadIdx.x == 0) bsum[blockIdx.x] = s[0] + s[1] + s[2] + s[3];
}

__global__ __launch_bounds__(512) void scanb_kernel(int* bsum, int NB)
{
    __shared__ int sh[512];
    int t = threadIdx.x;
    int v = (t < NB) ? bsum[t] : 0;
    sh[t] = v;
    __syncthreads();
    for (int o = 1; o < 512; o <<= 1) {
        int add = (t >= o) ? sh[t - o] : 0;
        __syncthreads();
        sh[t] += add;
        __syncthreads();
    }
    if (t < NB) bsum[t] = (t == 0) ? 0 : sh[t - 1];
}

__global__ __launch_bounds__(256) void scanfinal_kernel(
    const int* __restrict__ deg, const int* __restrict__ bsum,
    int* __restrict__ rowptr, int* __restrict__ cursor, int N)
{
    int b = blockIdx.x, t = threadIdx.x;
    int i = b * 256 + t;
    int v = (i < N) ? deg[i] : 0;
    __shared__ int sh[256];
    sh[t] = v;
    __syncthreads();
    for (int o = 1; o < 256; o <<= 1) {
        int add = (t >= o) ? sh[t - o] : 0;
        __syncthreads();
        sh[t] += add;
        __syncthreads();
    }
    int excl = sh[t] - v;
    if (i < N) {
        int rp = bsum[b] + excl;
        rowptr[i] = rp;
        cursor[i] = rp;
        if (i == N - 1) rowptr[N] = rp + v;
    }
}

__global__ __launch_bounds__(256) void fill_kernel(
    const int* __restrict__ ei, int* __restrict__ cursor, int* __restrict__ col, int E)
{
    int e = blockIdx.x * 256 + threadIdx.x;
    if (e >= E) return;
    int d = ei[E + e];
    int pos = atomicAdd(&cursor[d], 1);
    col[pos] = ei[e];
}

// Canonicalize: sort each row's col entries ascending -> gather sum order is a
// function of the multiset only (atomic fill order is scheduling-dependent).
__global__ __launch_bounds__(256) void sortrow_kernel(
    const int* __restrict__ rowptr, int* __restrict__ col, int N)
{
    int n = blockIdx.x * 256 + threadIdx.x;
    if (n >= N) return;
    int beg = rowptr[n], end = rowptr[n + 1];
    for (int i = beg + 1; i < end; ++i) {
        int v = col[i];
        int j = i - 1;
        while (j >= beg && col[j] > v) { col[j + 1] = col[j]; --j; }
        col[j + 1] = v;
    }
}

// ================= weight prepack: f32 [128][128] -> packed per-matrix [hi|lo] planes =================
__global__ __launch_bounds__(256) void prepack_kernel(
    const float* __restrict__ W0, const float* __restrict__ W1,
    const float* __restrict__ W2, const float* __restrict__ W3,
    const float* __restrict__ W4, const float* __restrict__ W5,
    ushort* __restrict__ wPk)
{
    int m = blockIdx.y;
    const float* W = (m == 0) ? W0 : (m == 1) ? W1 : (m == 2) ? W2
                   : (m == 3) ? W3 : (m == 4) ? W4 : W5;
    int base = m * 32768;
#pragma unroll
    for (int t = 0; t < 8; ++t) {
        int idx = blockIdx.x * 2048 + t * 256 + threadIdx.x;
        int j = idx & 7, l = (idx >> 3) & 63, cf = (idx >> 9) & 7, kb = idx >> 12;
        int k = kb * 32 + (l >> 4) * 8 + j;
        int n = cf * 16 + (l & 15);
        float v = W[k * 128 + n];
        ushort h = rn_bf16(v);
        wPk[base + idx] = h;
        wPk[base + 16384 + idx] = rn_bf16(v - bf16f(h));
    }
}

// ================= fused gather + dual MFMA linear + per-block stats (persistent) =================
// Y = agg(X)@Wl + X@Wr + bias.  Stats: per-block partials -> stPart (no atomics).
// r14/r18's PASSING launch geometry: __launch_bounds__(512,2), grid 512. DO NOT
// change geometry without re-verifying the tripwire (r15-r17 lesson).
template<int BN>
__global__ __launch_bounds__(512, 2) void glin_kernel(
    const float* __restrict__ X, const int* __restrict__ rowptr,
    const int* __restrict__ colIdx, const ushort* __restrict__ wPair,
    const float* __restrict__ bias, const float* __restrict__ bnst,
    float* __restrict__ Y, float* __restrict__ stPart, int nrows)
{
    // planes: [m][hi/lo][16 rows][136 bf16]; m0 = agg (Wl), m1 = root (Wr)
    __shared__ ushort ldsA[2 * 2 * 2176];
    const int tid  = threadIdx.x;
    const int lane = tid & 63;
    const int w    = tid >> 6;
    const int q = lane >> 4, s = lane & 15;

    // W fragments -> registers (once)
    bf16x8 wf[2][4][2];
#pragma unroll
    for (int m = 0; m < 2; ++m)
#pragma unroll
        for (int kb = 0; kb < 4; ++kb) {
            size_t o = (size_t)m * 32768 + (size_t)kb * 4096 + w * 512 + lane * 8;
            wf[m][kb][0] = *(const bf16x8*)(wPair + o);
            wf[m][kb][1] = *(const bf16x8*)(wPair + o + 16384);
        }

    const int srow  = tid >> 5;
    const int sunit = tid & 31;
    float4 bna, bnd;
    if (BN) {
        bna = *(const float4*)(bnst + 256 + sunit * 4);
        bnd = *(const float4*)(bnst + 384 + sunit * 4);
    }

    const int colc = w * 16 + s;
    const float bv = bias[colc];
    float cs = 0.f, cq = 0.f;

    const int NT = (nrows + 15) >> 4;
    const int stride = (int)gridDim.x;
    const int t0 = blockIdx.x;
    const int woff = srow * 136 + sunit * 4;

    auto stage = [&](int t) {
        int row = t * 16 + srow; if (row > nrows - 1) row = nrows - 1;
        float4 root = *(const float4*)(X + (size_t)row * 128 + sunit * 4);
        int beg = rowptr[row], end = rowptr[row + 1];
        float ax = 0.f, ay = 0.f, az = 0.f, aw = 0.f;
        float bx = 0.f, by = 0.f, bz = 0.f, bw = 0.f;
        int e = beg;
        for (; e + 2 <= end; e += 2) {
            int s0 = colIdx[e], s1 = colIdx[e + 1];
            float4 v0 = *(const float4*)(X + (size_t)s0 * 128 + sunit * 4);
            float4 v1 = *(const float4*)(X + (size_t)s1 * 128 + sunit * 4);
            if (BN) { v0 = bnrelu4(v0, bna, bnd); v1 = bnrelu4(v1, bna, bnd); }
            ax += v0.x; ay += v0.y; az += v0.z; aw += v0.w;
            bx += v1.x; by += v1.y; bz += v1.z; bw += v1.w;
        }
        if (e < end) {
            int s0 = colIdx[e];
            float4 v0 = *(const float4*)(X + (size_t)s0 * 128 + sunit * 4);
            if (BN) v0 = bnrelu4(v0, bna, bnd);
            ax += v0.x; ay += v0.y; az += v0.z; aw += v0.w;
        }
        float4 agg = make_float4(ax + bx, ay + by, az + bz, aw + bw);
        if (BN) root = bnrelu4(root, bna, bnd);
        ushort4 h, l;
        split4(agg, h, l);
        *(ushort4*)(ldsA + woff)        = h;
        *(ushort4*)(ldsA + 2176 + woff) = l;
        split4(root, h, l);
        *(ushort4*)(ldsA + 4352 + woff) = h;
        *(ushort4*)(ldsA + 6528 + woff) = l;
    };

    if (t0 < NT) stage(t0);

    for (int t = t0; t < NT; t += stride) {
        __syncthreads();   // staged planes visible

        f32x4 acc = (f32x4){0.f, 0.f, 0.f, 0.f};
#pragma unroll
        for (int m = 0; m < 2; ++m) {
            const ushort* pm = ldsA + m * 4352 + s * 136;
#pragma unroll
            for (int kb = 0; kb < 4; ++kb) {
                bf16x8 ah = *(const bf16x8*)(pm + (kb * 4 + q) * 8);
                bf16x8 al = *(const bf16x8*)(pm + 2176 + (kb * 4 + q) * 8);
                acc = __builtin_amdgcn_mfma_f32_16x16x32_bf16(ah, wf[m][kb][0], acc, 0, 0, 0);
                acc = __builtin_amdgcn_mfma_f32_16x16x32_bf16(al, wf[m][kb][0], acc, 0, 0, 0);
                acc = __builtin_amdgcn_mfma_f32_16x16x32_bf16(ah, wf[m][kb][1], acc, 0, 0, 0);
            }
        }

        int r0 = t * 16 + q * 4;
#pragma unroll
        for (int i = 0; i < 4; ++i) {
            int r = r0 + i;
            if (r < nrows) {
                float y = acc[i] + bv;
                Y[(size_t)r * 128 + colc] = y;
                cs += y; cq += y * y;
            }
        }
        __syncthreads();   // plane reads done
        int tn = t + stride;
        if (tn < NT) stage(tn);
    }

    // per-block partials, fixed shfl tree, no atomics -> deterministic
    cs += __shfl_xor(cs, 16); cs += __shfl_xor(cs, 32);
    cq += __shfl_xor(cq, 16); cq += __shfl_xor(cq, 32);
    if (q == 0) {
        stPart[(size_t)blockIdx.x * 256 + colc]       = cs;
        stPart[(size_t)blockIdx.x * 256 + 128 + colc] = cq;
    }
}

// ================= BN finalize: parallel fixed-tree reduce of partials -> affine =================
// Grid = 128 blocks (one per column). Thread j accumulates partials b = j, j+256, ...
// (fixed per-thread order), then a fixed-shape LDS tree reduces 256 -> 1. Structure is
// data-independent -> bitwise deterministic. Replaces r18's single-block serial loop
// (512 dependent-latency loads/thread = 120 us).
__global__ __launch_bounds__(256) void finalize_kernel(
    const float* __restrict__ stPart, int nblocks, float* st,
    const float* __restrict__ g, const float* __restrict__ be, float inv_n)
{
    __shared__ float ssum[256], ssq[256];
    const int c = blockIdx.x;        // column 0..127
    const int j = threadIdx.x;       // 0..255
    float s0 = 0.f, q0 = 0.f;
    for (int b = j; b < nblocks; b += 256) {   // fixed order per thread
        s0 += stPart[(size_t)b * 256 + c];
        q0 += stPart[(size_t)b * 256 + 128 + c];
    }
    ssum[j] = s0; ssq[j] = q0;
    __syncthreads();
#pragma unroll
    for (int o = 128; o > 0; o >>= 1) {        // fixed tree
        if (j < o) { ssum[j] += ssum[j + o]; ssq[j] += ssq[j + o]; }
        __syncthreads();
    }
    if (j == 0) {
        float mu = ssum[0] * inv_n;
        float var = ssq[0] * inv_n - mu * mu;
        float rs = rsqrtf(var + EPS);
        float a = g[c] * rs;
        st[256 + c] = a;
        st[384 + c] = be[c] - mu * a;
    }
}

// ================= fused MLP head: out = relu(relu(bnrelu(X)@W1+b1)@W2+b2)@W3+b3 =================
__global__ __launch_bounds__(512, 2) void mlp_kernel(
    const float* __restrict__ X, const ushort* __restrict__ w1Pk,
    const ushort* __restrict__ w2Pk, const float* __restrict__ b1,
    const float* __restrict__ b2, const float* __restrict__ W3,
    const float* __restrict__ b3, const float* __restrict__ bnst,
    float* __restrict__ out, int nrows)
{
    __shared__ ushort ldsP[2 * 2176];    // hi/lo planes for current GEMM input
    __shared__ float  ldsY[16 * 132];    // y tile (132-pad)
    const int tid  = threadIdx.x;
    const int lane = tid & 63;
    const int w    = tid >> 6;
    const int q = lane >> 4, s = lane & 15;

    bf16x8 wf1[4][2], wf2[4][2];
#pragma unroll
    for (int kb = 0; kb < 4; ++kb) {
        size_t o = (size_t)kb * 4096 + w * 512 + lane * 8;
        wf1[kb][0] = *(const bf16x8*)(w1Pk + o);
        wf1[kb][1] = *(const bf16x8*)(w1Pk + o + 16384);
        wf2[kb][0] = *(const bf16x8*)(w2Pk + o);
        wf2[kb][1] = *(const bf16x8*)(w2Pk + o + 16384);
    }

    const int srow  = tid >> 5;
    const int sunit = tid & 31;
    float4 bna = *(const float4*)(bnst + 256 + sunit * 4);
    float4 bnd = *(const float4*)(bnst + 384 + sunit * 4);

    float w30[4], w31[4];
#pragma unroll
    for (int j = 0; j < 4; ++j) {
        w30[j] = W3[(sunit * 4 + j) * 2];
        w31[j] = W3[(sunit * 4 + j) * 2 + 1];
    }
    const float b30 = b3[0], b31 = b3[1];

    const int colc = w * 16 + s;
    const float bv1 = b1[colc];
    const float bv2 = b2[colc];

    const int NT = (nrows + 15) >> 4;
    const int stride = (int)gridDim.x;
    const int t0 = blockIdx.x;
    const int woff = srow * 136 + sunit * 4;

    auto stageX = [&](int t) {
        int row = t * 16 + srow; if (row > nrows - 1) row = nrows - 1;
        float4 v = *(const float4*)(X + (size_t)row * 128 + sunit * 4);
        v = bnrelu4(v, bna, bnd);
        ushort4 h, l;
        split4(v, h, l);
        *(ushort4*)(ldsP + woff)        = h;
        *(ushort4*)(ldsP + 2176 + woff) = l;
    };

    auto gemm = [&](const bf16x8 (&wf)[4][2]) {
        f32x4 acc = (f32x4){0.f, 0.f, 0.f, 0.f};
        const ushort* pm = ldsP + s * 136;
#pragma unroll
        for (int kb = 0; kb < 4; ++kb) {
            bf16x8 ah = *(const bf16x8*)(pm + (kb * 4 + q) * 8);
            bf16x8 al = *(const bf16x8*)(pm + 2176 + (kb * 4 + q) * 8);
            acc = __builtin_amdgcn_mfma_f32_16x16x32_bf16(ah, wf[kb][0], acc, 0, 0, 0);
            acc = __builtin_amdgcn_mfma_f32_16x16x32_bf16(al, wf[kb][0], acc, 0, 0, 0);
            acc = __builtin_amdgcn_mfma_f32_16x16x32_bf16(ah, wf[kb][1], acc, 0, 0, 0);
        }
        return acc;
    };

    if (t0 < NT) stageX(t0);

    for (int t = t0; t < NT; t += stride) {
        __syncthreads();                         // (a) planes(X) ready; prev dot's ldsY reads done

        f32x4 acc = gemm(wf1);
#pragma unroll
        for (int i = 0; i < 4; ++i)
            ldsY[(q * 4 + i) * 132 + colc] = fmaxf(acc[i] + bv1, 0.f);
        __syncthreads();                         // (c) y1 ready; planes(X) reads done

        {   // re-split y1 -> planes
            float4 yv = *(const float4*)&ldsY[srow * 132 + sunit * 4];
            ushort4 h, l;
            split4(yv, h, l);
            *(ushort4*)(ldsP + woff)        = h;
            *(ushort4*)(ldsP + 2176 + woff) = l;
        }
        __syncthreads();                         // (d) planes(y1) ready; y1 reads done

        acc = gemm(wf2);
#pragma unroll
        for (int i = 0; i < 4; ++i)
            ldsY[(q * 4 + i) * 132 + colc] = fmaxf(acc[i] + bv2, 0.f);
        __syncthreads();                         // (e) y2 ready; planes(y1) reads done

        {   // per-row projection to DOUT=2 (fixed shfl order -> deterministic)
            float4 yv = *(const float4*)&ldsY[srow * 132 + sunit * 4];
            float p0 = yv.x * w30[0] + yv.y * w30[1] + yv.z * w30[2] + yv.w * w30[3];
            float p1 = yv.x * w31[0] + yv.y * w31[1] + yv.z * w31[2] + yv.w * w31[3];
#pragma unroll
            for (int o = 1; o < 32; o <<= 1) {
                p0 += __shfl_xor(p0, o);
                p1 += __shfl_xor(p1, o);
            }
            int row = t * 16 + srow;
            if (sunit == 0 && row < nrows)
                *(float2*)(out + (size_t)row * 2) = make_float2(p0 + b30, p1 + b31);
        }
        int tn = t + stride;
        if (tn < NT) stageX(tn);                 // writes ldsP (reads done at (e))
    }
}

extern "C" void kernel_launch(void* const* d_in, const int* in_sizes, int n_in,
                              void* d_out, int out_size, void* d_ws, size_t ws_size,
                              hipStream_t stream) {
    const float* x   = (const float*)d_in[0];
    const int*   ei  = (const int*)d_in[1];
    const float* Wl0 = (const float*)d_in[2];
    const float* bl0 = (const float*)d_in[3];
    const float* Wr0 = (const float*)d_in[4];
    const float* Wl1 = (const float*)d_in[5];
    const float* bl1 = (const float*)d_in[6];
    const float* Wr1 = (const float*)d_in[7];
    const float* g0  = (const float*)d_in[8];
    const float* be0 = (const float*)d_in[9];
    const float* g1  = (const float*)d_in[10];
    const float* be1 = (const float*)d_in[11];
    const float* W1  = (const float*)d_in[12];
    const float* b1  = (const float*)d_in[13];
    const float* W2  = (const float*)d_in[14];
    const float* b2  = (const float*)d_in[15];
    const float* W3  = (const float*)d_in[16];
    const float* b3  = (const float*)d_in[17];
    float* out = (float*)d_out;

    const int N = in_sizes[0] / 128;
    const int E = in_sizes[1] / 2;
    const int GLIN_GRID = 512;

    // workspace layout
    float* A   = (float*)d_ws;                   // [N,128]
    float* B   = A + (size_t)N * 128;            // [N,128]
    float* st0 = B + (size_t)N * 128;            // 512 floats
    float* st1 = st0 + 512;                      // 512 floats
    float* stPart = st1 + 512;                   // GLIN_GRID * 256
    ushort* wPk = (ushort*)(stPart + (size_t)GLIN_GRID * 256);   // 6 * 32768
    int* deg    = (int*)(wPk + 6 * 32768);       // N
    int* rowptr = deg + N;                       // N+1
    int* cursor = rowptr + N + 1;                // N
    int* col    = cursor + N;                    // E
    int* bsum   = col + E;                       // <=512

    const int edgeGrid = (E + 255) / 256;
    const int nodeGrid = (N + 255) / 256;
    const float inv_n = 1.0f / (float)N;

    // matrix slots: 0=Wl0 1=Wr0 2=Wl1 3=Wr1 4=W1 5=W2 (dual pairs adjacent)
    prepack_kernel<<<dim3(8, 6), 256, 0, stream>>>(Wl0, Wr0, Wl1, Wr1, W1, W2, wPk);

    // ----- CSR build (canonicalized: per-row sort -> deterministic sum order) -----
    hipMemsetAsync(deg, 0, (size_t)N * sizeof(int), stream);
    hist_kernel<<<edgeGrid, 256, 0, stream>>>(ei, deg, E);
    blocksum_kernel<<<nodeGrid, 256, 0, stream>>>(deg, bsum, N);
    scanb_kernel<<<1, 512, 0, stream>>>(bsum, nodeGrid);
    scanfinal_kernel<<<nodeGrid, 256, 0, stream>>>(deg, bsum, rowptr, cursor, N);
    fill_kernel<<<edgeGrid, 256, 0, stream>>>(ei, cursor, col, E);
    sortrow_kernel<<<nodeGrid, 256, 0, stream>>>(rowptr, col, N);

    // ----- layer 0: A = agg(x)@Wl0 + x@Wr0 + bl0 (fused gather+lin), partials -> finalize -----
    glin_kernel<0><<<GLIN_GRID, 512, 0, stream>>>(
        x, rowptr, col, wPk, bl0, nullptr, A, stPart, N);
    finalize_kernel<<<128, 256, 0, stream>>>(stPart, GLIN_GRID, st0, g0, be0, inv_n);

    // ----- layer 1: B = agg(bn0(A))@Wl1 + bn0(A)@Wr1 + bl1 -----
    glin_kernel<1><<<GLIN_GRID, 512, 0, stream>>>(
        A, rowptr, col, wPk + 2 * 32768, bl1, st0, B, stPart, N);
    finalize_kernel<<<128, 256, 0, stream>>>(stPart, GLIN_GRID, st1, g1, be1, inv_n);

    // ----- fused MLP head + projection -----
    mlp_kernel<<<GLIN_GRID, 512, 0, stream>>>(
        B, wPk + 4 * 32768, wPk + 5 * 32768, b1, b2, W3, b3, st1, out, N);
}